// Round 2
// baseline (396.503 us; speedup 1.0000x reference)
//
#include <hip/hip_runtime.h>
#include <hip/hip_bf16.h>
#include <stdint.h>

// Problem constants (from reference)
constexpr int B_ = 64;
constexpr int P_ = 65536;
constexpr int NEGPOS_ = 7;
constexpr int NBINS = 4096;       // float bits >> 19 (sign+exp+4 mantissa bits), clamped
constexpr int CHUNK = 4096;       // anchors per block in kernel A
constexpr int CPR = P_ / CHUNK;   // 16 chunks per row

// Workspace layout
constexpr size_t OFF_HCNT   = 0;                                   // 64*4096 u32
constexpr size_t OFF_HSUM   = (size_t)B_ * NBINS * 4;              // 64*4096 f32
constexpr size_t OFF_ROWPOS = OFF_HSUM + (size_t)B_ * NBINS * 4;   // 64 u32 (256B)
constexpr size_t OFF_ROWNEG = OFF_ROWPOS + 256;                    // 64 f32 (256B)
constexpr size_t OFF_ACC    = OFF_ROWNEG + 256;                    // 4 doubles
constexpr size_t OFF_CNTS   = OFF_ACC + 4 * 8;                     // 3 u32
constexpr size_t WS_ZERO    = OFF_CNTS + 16;

__device__ __forceinline__ float smooth_l1(float t, float p) {
    float ad = fabsf(t - p);
    return ad < 1.0f ? 0.5f * ad * ad : ad - 0.5f;
}

__global__ __launch_bounds__(256) void multibox_main(
    const float* __restrict__ boxes_p, const float* __restrict__ conf_p,
    const float* __restrict__ kpts_p,  const float* __restrict__ dpth_p,
    const float* __restrict__ boxes_t, const float* __restrict__ kypts_t,
    const float* __restrict__ dpths_t, const int* __restrict__ label,
    unsigned* __restrict__ g_hcnt, float* __restrict__ g_hsum,
    unsigned* __restrict__ rowpos, double* __restrict__ acc,
    unsigned* __restrict__ cnts)
{
    __shared__ unsigned hcnt[NBINS];
    __shared__ float    hsum[NBINS];

    const int row   = blockIdx.x / CPR;
    const int chunk = blockIdx.x % CPR;

    for (int i = threadIdx.x; i < NBINS; i += 256) { hcnt[i] = 0u; hsum[i] = 0.f; }
    __syncthreads();

    const long long base = (long long)row * P_ + (long long)chunk * CHUNK;

    float l_box = 0.f, l_lm = 0.f, l_dp = 0.f, l_ce = 0.f;
    unsigned c_box = 0, c_lm = 0, c_dp = 0, c_pos = 0;

    for (int it = 0; it < CHUNK / 256; ++it) {
        const long long i = base + (long long)it * 256 + threadIdx.x;
        const int lab = label[i];
        const float2 c = ((const float2*)conf_p)[i];
        const float m  = fmaxf(c.x, c.y);
        const float mn = fminf(c.x, c.y);
        const float lse = m + log1pf(expf(mn - m));

        if (lab != 0) {
            // positive anchor: confidence CE with label=1, plus smooth-L1 terms
            c_pos++;
            l_ce += lse - c.y;

            const float4 bt = ((const float4*)boxes_t)[i];
            const float4 bp = ((const float4*)boxes_p)[i];
            {
                float tv[4] = {bt.x, bt.y, bt.z, bt.w};
                float pv[4] = {bp.x, bp.y, bp.z, bp.w};
                #pragma unroll
                for (int e = 0; e < 4; ++e) {
                    if (!__builtin_isnan(tv[e])) { c_box++; l_box += smooth_l1(tv[e], pv[e]); }
                }
            }
            const float2* kt = ((const float2*)kypts_t) + i * 5;
            const float2* kp = ((const float2*)kpts_p)  + i * 5;
            #pragma unroll
            for (int e = 0; e < 5; ++e) {
                float2 t2 = kt[e], p2 = kp[e];
                if (!__builtin_isnan(t2.x)) { c_lm++; l_lm += smooth_l1(t2.x, p2.x); }
                if (!__builtin_isnan(t2.y)) { c_lm++; l_lm += smooth_l1(t2.y, p2.y); }
            }
            const float2 dt = ((const float2*)dpths_t)[i];
            const float2 dp = ((const float2*)dpth_p)[i];
            if (!__builtin_isnan(dt.x)) { c_dp++; l_dp += smooth_l1(dt.x, dp.x); }
            if (!__builtin_isnan(dt.y)) { c_dp++; l_dp += smooth_l1(dt.y, dp.y); }
        } else {
            // negative anchor: mining loss = lse - conf[...,0]  (label 0)
            float lc = fmaxf(lse - c.x, 0.f);
            unsigned bin = __float_as_uint(lc) >> 19;
            if (bin > NBINS - 1) bin = NBINS - 1;
            atomicAdd(&hcnt[bin], 1u);
            atomicAdd(&hsum[bin], lc);
        }
    }

    // wave-level reduction of scalars, one global atomic per wave
    #pragma unroll
    for (int o = 32; o > 0; o >>= 1) {
        l_box += __shfl_down(l_box, o);
        l_lm  += __shfl_down(l_lm, o);
        l_dp  += __shfl_down(l_dp, o);
        l_ce  += __shfl_down(l_ce, o);
        c_box += __shfl_down(c_box, o);
        c_lm  += __shfl_down(c_lm, o);
        c_dp  += __shfl_down(c_dp, o);
        c_pos += __shfl_down(c_pos, o);
    }
    if ((threadIdx.x & 63) == 0) {
        atomicAdd(&acc[0], (double)l_box);
        atomicAdd(&acc[1], (double)l_lm);
        atomicAdd(&acc[2], (double)l_dp);
        atomicAdd(&acc[3], (double)l_ce);
        if (c_box) atomicAdd(&cnts[0], c_box);
        if (c_lm)  atomicAdd(&cnts[1], c_lm);
        if (c_dp)  atomicAdd(&cnts[2], c_dp);
        if (c_pos) atomicAdd(&rowpos[row], c_pos);
    }

    __syncthreads();
    // flush LDS histogram (sparse) to per-row global histogram
    for (int i = threadIdx.x; i < NBINS; i += 256) {
        unsigned c = hcnt[i];
        if (c) {
            atomicAdd(&g_hcnt[row * NBINS + i], c);
            atomicAdd(&g_hsum[row * NBINS + i], hsum[i]);
        }
    }
}

// Per-row top-k (k = min(7*num_pos, P-1)) sum of mining losses via histogram select.
__global__ __launch_bounds__(256) void multibox_select(
    const unsigned* __restrict__ g_hcnt, const float* __restrict__ g_hsum,
    const unsigned* __restrict__ rowpos, float* __restrict__ rowneg)
{
    const int b = blockIdx.x;
    const int j = threadIdx.x;   // 256 threads; thread j owns bins [4095-16j-15 .. 4095-16j] (descending)
    const unsigned* hc = g_hcnt + (size_t)b * NBINS;
    const float*    hs = g_hsum + (size_t)b * NBINS;

    long long k = (long long)NEGPOS_ * (long long)rowpos[b];
    if (k > P_ - 1) k = P_ - 1;

    const int binhi = NBINS - 1 - j * 16;
    unsigned segc = 0; float segs = 0.f;
    #pragma unroll
    for (int i = 0; i < 16; ++i) { segc += hc[binhi - i]; segs += hs[binhi - i]; }

    __shared__ unsigned sc[256];
    __shared__ float    ss[256];
    sc[j] = segc; ss[j] = segs;
    __syncthreads();
    // Hillis-Steele inclusive scan over thread segments (descending-bin order)
    for (int off = 1; off < 256; off <<= 1) {
        unsigned cadd = (j >= off) ? sc[j - off] : 0u;
        float    sadd = (j >= off) ? ss[j - off] : 0.f;
        __syncthreads();
        sc[j] += cadd; ss[j] += sadd;
        __syncthreads();
    }
    const unsigned incl  = sc[j];
    const unsigned excl  = incl - segc;
    const float    incls = ss[j];
    const float    excls = incls - segs;
    const unsigned total  = sc[255];
    const float    totals = ss[255];

    if (k <= 0) { if (j == 0) rowneg[b] = 0.f; return; }
    if ((long long)total <= k) { if (j == 0) rowneg[b] = totals; return; }

    if ((long long)excl < k && k <= (long long)incl) {
        unsigned cum = excl; float cums = excls;
        float res = 0.f;
        for (int i = 0; i < 16; ++i) {
            const int bin = binhi - i;
            const unsigned c = hc[bin];
            const float    s = hs[bin];
            if ((long long)(cum + c) >= k) {
                const unsigned r = (unsigned)(k - cum);
                res = cums + (c ? (s / (float)c) * (float)r : 0.f);
                break;
            }
            cum += c; cums += s;
        }
        rowneg[b] = res;
    }
}

__global__ void multibox_finalize(
    const unsigned* __restrict__ rowpos, const float* __restrict__ rowneg,
    const double* __restrict__ acc, const unsigned* __restrict__ cnts,
    float* __restrict__ out)
{
    const int t = threadIdx.x; // 64 threads = 1 wave
    float npf = (float)rowpos[t];
    float ng  = rowneg[t];
    #pragma unroll
    for (int o = 32; o > 0; o >>= 1) {
        npf += __shfl_down(npf, o);
        ng  += __shfl_down(ng, o);
    }
    if (t == 0) {
        unsigned cl = cnts[0]; if (!cl) cl = 1;
        unsigned cm = cnts[1]; if (!cm) cm = 1;
        unsigned cd = cnts[2]; if (!cd) cd = 1;
        float n = npf > 1.f ? npf : 1.f;
        out[0] = (float)(acc[0] / (double)cl);
        out[1] = (float)((acc[3] + (double)ng) / (double)n);
        out[2] = (float)(acc[1] / (double)cm);
        out[3] = (float)(acc[2] / (double)cd);
    }
}

extern "C" void kernel_launch(void* const* d_in, const int* in_sizes, int n_in,
                              void* d_out, int out_size, void* d_ws, size_t ws_size,
                              hipStream_t stream) {
    const float* boxes_p = (const float*)d_in[0];
    const float* conf_p  = (const float*)d_in[1];
    const float* kpts_p  = (const float*)d_in[2];
    const float* dpth_p  = (const float*)d_in[3];
    const float* boxes_t = (const float*)d_in[4];
    const float* kypts_t = (const float*)d_in[5];
    const float* dpths_t = (const float*)d_in[6];
    const int*   label   = (const int*)d_in[7];
    float* out = (float*)d_out;

    uint8_t* ws = (uint8_t*)d_ws;
    unsigned* g_hcnt  = (unsigned*)(ws + OFF_HCNT);
    float*    g_hsum  = (float*)(ws + OFF_HSUM);
    unsigned* rowpos  = (unsigned*)(ws + OFF_ROWPOS);
    float*    rowneg  = (float*)(ws + OFF_ROWNEG);
    double*   acc     = (double*)(ws + OFF_ACC);
    unsigned* cnts    = (unsigned*)(ws + OFF_CNTS);

    hipMemsetAsync(d_ws, 0, WS_ZERO, stream);

    multibox_main<<<B_ * CPR, 256, 0, stream>>>(
        boxes_p, conf_p, kpts_p, dpth_p, boxes_t, kypts_t, dpths_t, label,
        g_hcnt, g_hsum, rowpos, acc, cnts);

    multibox_select<<<B_, 256, 0, stream>>>(g_hcnt, g_hsum, rowpos, rowneg);

    multibox_finalize<<<1, 64, 0, stream>>>(rowpos, rowneg, acc, cnts, out);
}

// Round 3
// 102.933 us; speedup vs baseline: 3.8520x; 3.8520x over previous
//
#include <hip/hip_runtime.h>
#include <stdint.h>

constexpr int B_ = 64;
constexpr int P_ = 65536;
constexpr int NEGPOS_ = 7;
constexpr int NBINS = 1024;        // linear bins of d = c1 - c0 over [-4, 6]
constexpr int CHUNK = 4096;        // anchors per block
constexpr int CPR = P_ / CHUNK;    // 16 chunks per row
constexpr int NBLK = B_ * CPR;     // 1024 blocks

// bin(d) = clamp((int)(d*102.4 + 409.6), 0, 1023) -- identical fmaf in all kernels
__device__ __forceinline__ int bin_of(float d) {
    int b = (int)fmaf(d, 102.4f, 409.6f);
    return b < 0 ? 0 : (b > NBINS - 1 ? NBINS - 1 : b);
}
__device__ __forceinline__ float softplus(float x) {
    return fmaxf(x, 0.f) + log1pf(expf(-fabsf(x)));
}
__device__ __forceinline__ float smooth_l1(float t, float p) {
    float ad = fabsf(t - p);
    return ad < 1.0f ? 0.5f * ad * ad : ad - 0.5f;
}

// Workspace layout (all regions fully overwritten each call; no memset needed)
constexpr size_t OFF_HIST  = 0;                               // NBLK*NBINS u16  (2 MB)
constexpr size_t OFF_BPART = OFF_HIST + (size_t)NBLK * NBINS * 2;   // NBLK*4 f32
constexpr size_t OFF_BCNT  = OFF_BPART + (size_t)NBLK * 16;         // NBLK*4 u32
constexpr size_t OFF_TB    = OFF_BCNT + (size_t)NBLK * 16;          // 64 i32
constexpr size_t OFF_SCALE = OFF_TB + 256;                          // 64 f32
constexpr size_t OFF_PART2 = OFF_SCALE + 256;                       // NBLK f32

// ---------------- Pass 1: positives' losses + per-block count histogram of d ----
__global__ __launch_bounds__(256) void multibox_pass1(
    const float* __restrict__ boxes_p, const float* __restrict__ conf_p,
    const float* __restrict__ kpts_p,  const float* __restrict__ dpth_p,
    const float* __restrict__ boxes_t, const float* __restrict__ kypts_t,
    const float* __restrict__ dpths_t, const int* __restrict__ label,
    uint16_t* __restrict__ hist, float* __restrict__ bpart, unsigned* __restrict__ bcnt)
{
    __shared__ unsigned hcnt[NBINS];
    __shared__ float    redf[4][4];
    __shared__ unsigned redu[4][4];

    const int blk = blockIdx.x;
    const int row = blk / CPR, chunk = blk % CPR;
    const int t = threadIdx.x;

    #pragma unroll
    for (int i = 0; i < NBINS / 256; ++i) hcnt[t + i * 256] = 0u;
    __syncthreads();

    const long long base = (long long)row * P_ + (long long)chunk * CHUNK;

    float l_box = 0.f, l_lm = 0.f, l_dp = 0.f, l_ce = 0.f;
    unsigned c_box = 0, c_lm = 0, c_dp = 0, c_pos = 0;

    for (int it = 0; it < CHUNK / 256; ++it) {
        const long long i = base + (long long)it * 256 + t;
        const int lab = label[i];
        const float2 c = ((const float2*)conf_p)[i];
        const float d = c.y - c.x;

        if (lab != 0) {
            c_pos++;
            l_ce += softplus(-d);  // lse - c.y

            const float4 bt = ((const float4*)boxes_t)[i];
            const float4 bp = ((const float4*)boxes_p)[i];
            {
                float tv[4] = {bt.x, bt.y, bt.z, bt.w};
                float pv[4] = {bp.x, bp.y, bp.z, bp.w};
                #pragma unroll
                for (int e = 0; e < 4; ++e)
                    if (!__builtin_isnan(tv[e])) { c_box++; l_box += smooth_l1(tv[e], pv[e]); }
            }
            const float2* kt = ((const float2*)kypts_t) + i * 5;
            const float2* kp = ((const float2*)kpts_p)  + i * 5;
            #pragma unroll
            for (int e = 0; e < 5; ++e) {
                float2 t2 = kt[e], p2 = kp[e];
                if (!__builtin_isnan(t2.x)) { c_lm++; l_lm += smooth_l1(t2.x, p2.x); }
                if (!__builtin_isnan(t2.y)) { c_lm++; l_lm += smooth_l1(t2.y, p2.y); }
            }
            const float2 dt = ((const float2*)dpths_t)[i];
            const float2 dp = ((const float2*)dpth_p)[i];
            if (!__builtin_isnan(dt.x)) { c_dp++; l_dp += smooth_l1(dt.x, dp.x); }
            if (!__builtin_isnan(dt.y)) { c_dp++; l_dp += smooth_l1(dt.y, dp.y); }
        } else {
            atomicAdd(&hcnt[bin_of(d)], 1u);   // near-uniform bins -> ~conflict-free
        }
    }

    // wave reduce (64 lanes), then cross-wave via LDS, thread 0 stores block slots
    #pragma unroll
    for (int o = 32; o > 0; o >>= 1) {
        l_box += __shfl_down(l_box, o);
        l_lm  += __shfl_down(l_lm, o);
        l_dp  += __shfl_down(l_dp, o);
        l_ce  += __shfl_down(l_ce, o);
        c_box += __shfl_down(c_box, o);
        c_lm  += __shfl_down(c_lm, o);
        c_dp  += __shfl_down(c_dp, o);
        c_pos += __shfl_down(c_pos, o);
    }
    const int wid = t >> 6;
    if ((t & 63) == 0) {
        redf[wid][0] = l_box; redf[wid][1] = l_lm; redf[wid][2] = l_dp; redf[wid][3] = l_ce;
        redu[wid][0] = c_box; redu[wid][1] = c_lm; redu[wid][2] = c_dp; redu[wid][3] = c_pos;
    }
    __syncthreads();
    if (t == 0) {
        float f0 = 0, f1 = 0, f2 = 0, f3 = 0; unsigned u0 = 0, u1 = 0, u2 = 0, u3 = 0;
        #pragma unroll
        for (int w = 0; w < 4; ++w) {
            f0 += redf[w][0]; f1 += redf[w][1]; f2 += redf[w][2]; f3 += redf[w][3];
            u0 += redu[w][0]; u1 += redu[w][1]; u2 += redu[w][2]; u3 += redu[w][3];
        }
        float4* bp4 = (float4*)(bpart + (size_t)blk * 4);
        *bp4 = make_float4(f0, f1, f2, f3);
        uint4* bc4 = (uint4*)(bcnt + (size_t)blk * 4);
        *bc4 = make_uint4(u0, u1, u2, u3);
    }

    // flush full histogram (counts <= 4096 < 65536, u16 safe), plain stores
    uint16_t* hb = hist + (size_t)blk * NBINS;
    #pragma unroll
    for (int i = 0; i < NBINS / 256 / 4; ++i) { } // (NBINS/256==4 handled below)
    {
        const int b0 = t * 4;
        ushort4 v;
        v.x = (uint16_t)hcnt[b0 + 0];
        v.y = (uint16_t)hcnt[b0 + 1];
        v.z = (uint16_t)hcnt[b0 + 2];
        v.w = (uint16_t)hcnt[b0 + 3];
        *(ushort4*)(hb + b0) = v;
    }
}

// ---------------- Select: per-row threshold bin + boundary scale ----------------
__global__ __launch_bounds__(256) void multibox_select(
    const uint16_t* __restrict__ hist, const unsigned* __restrict__ bcnt,
    int* __restrict__ rowtb, float* __restrict__ rowscale)
{
    const int r = blockIdx.x, j = threadIdx.x;
    const uint16_t* hb = hist + (size_t)r * CPR * NBINS;

    unsigned c0 = 0, c1 = 0, c2 = 0, c3 = 0;   // my 4 bins: 4j .. 4j+3
    for (int ch = 0; ch < CPR; ++ch) {
        ushort4 v = *(const ushort4*)(hb + (size_t)ch * NBINS + 4 * j);
        c0 += v.x; c1 += v.y; c2 += v.z; c3 += v.w;
    }
    const unsigned seg = c0 + c1 + c2 + c3;

    __shared__ unsigned sc[256];
    sc[j] = seg;
    __syncthreads();
    // inclusive suffix scan: sc[j] = sum_{j' >= j} seg_{j'}
    for (int off = 1; off < 256; off <<= 1) {
        unsigned add = (j + off < 256) ? sc[j + off] : 0u;
        __syncthreads();
        sc[j] += add;
        __syncthreads();
    }
    const unsigned Tj = sc[j];
    const unsigned T0 = sc[0];

    __shared__ unsigned snp;
    if (j == 0) {
        unsigned s = 0;
        for (int c = 0; c < CPR; ++c) s += bcnt[(size_t)(r * CPR + c) * 4 + 3];
        snp = s;
    }
    __syncthreads();

    long long k = (long long)NEGPOS_ * (long long)snp;
    if (k > P_ - 1) k = P_ - 1;

    if (j == 0) {
        if (k <= 0)                    { rowtb[r] = NBINS; rowscale[r] = 0.f; }
        else if ((long long)T0 < k)    { rowtb[r] = -1;    rowscale[r] = 0.f; }
    }
    const unsigned above = Tj - seg;   // count in bins > my segment
    if (k > 0 && (long long)above < k && k <= (long long)Tj) {
        unsigned cum = above;
        const unsigned cs[4]   = {c3, c2, c1, c0};
        const int      bins[4] = {4 * j + 3, 4 * j + 2, 4 * j + 1, 4 * j};
        #pragma unroll
        for (int i = 0; i < 4; ++i) {
            if ((long long)(cum + cs[i]) >= k) {
                rowtb[r] = bins[i];
                unsigned rr = (unsigned)(k - cum);
                rowscale[r] = cs[i] ? (float)rr / (float)cs[i] : 0.f;
                break;
            }
            cum += cs[i];
        }
    }
}

// ---------------- Pass 2: sum softplus(d) over mined negatives ------------------
__global__ __launch_bounds__(256) void multibox_pass2(
    const float* __restrict__ conf_p, const int* __restrict__ label,
    const int* __restrict__ rowtb, const float* __restrict__ rowscale,
    float* __restrict__ part2)
{
    const int blk = blockIdx.x;
    const int row = blk / CPR, chunk = blk % CPR;
    const int t = threadIdx.x;
    const int tb = rowtb[row];
    const float scl = rowscale[row];
    const long long base = (long long)row * P_ + (long long)chunk * CHUNK;

    float sa = 0.f, sb = 0.f;
    for (int it = 0; it < CHUNK / 256; ++it) {
        const long long i = base + (long long)it * 256 + t;
        const int lab = label[i];
        const float2 c = ((const float2*)conf_p)[i];
        const float d = c.y - c.x;
        const int bin = bin_of(d);
        if (lab == 0 && bin >= tb) {
            const float v = softplus(d);
            if (bin > tb) sa += v; else sb += v;
        }
    }
    float v = sa + scl * sb;
    #pragma unroll
    for (int o = 32; o > 0; o >>= 1) v += __shfl_down(v, o);

    __shared__ float red[4];
    const int wid = t >> 6;
    if ((t & 63) == 0) red[wid] = v;
    __syncthreads();
    if (t == 0) part2[blk] = red[0] + red[1] + red[2] + red[3];
}

// ---------------- Finalize ------------------------------------------------------
__global__ __launch_bounds__(256) void multibox_final(
    const float* __restrict__ bpart, const unsigned* __restrict__ bcnt,
    const float* __restrict__ part2, float* __restrict__ out)
{
    const int t = threadIdx.x;
    float f0 = 0, f1 = 0, f2 = 0, f3 = 0, s2 = 0;
    unsigned u0 = 0, u1 = 0, u2 = 0, u3 = 0;
    for (int i = t; i < NBLK; i += 256) {
        float4 bp = ((const float4*)bpart)[i];
        uint4  bc = ((const uint4*)bcnt)[i];
        f0 += bp.x; f1 += bp.y; f2 += bp.z; f3 += bp.w;
        u0 += bc.x; u1 += bc.y; u2 += bc.z; u3 += bc.w;
        s2 += part2[i];
    }
    #pragma unroll
    for (int o = 32; o > 0; o >>= 1) {
        f0 += __shfl_down(f0, o); f1 += __shfl_down(f1, o);
        f2 += __shfl_down(f2, o); f3 += __shfl_down(f3, o);
        s2 += __shfl_down(s2, o);
        u0 += __shfl_down(u0, o); u1 += __shfl_down(u1, o);
        u2 += __shfl_down(u2, o); u3 += __shfl_down(u3, o);
    }
    __shared__ float rf[4][5];
    __shared__ unsigned ru[4][4];
    const int wid = t >> 6;
    if ((t & 63) == 0) {
        rf[wid][0] = f0; rf[wid][1] = f1; rf[wid][2] = f2; rf[wid][3] = f3; rf[wid][4] = s2;
        ru[wid][0] = u0; ru[wid][1] = u1; ru[wid][2] = u2; ru[wid][3] = u3;
    }
    __syncthreads();
    if (t == 0) {
        float F0 = 0, F1 = 0, F2 = 0, F3 = 0, S2 = 0;
        unsigned U0 = 0, U1 = 0, U2 = 0, U3 = 0;
        #pragma unroll
        for (int w = 0; w < 4; ++w) {
            F0 += rf[w][0]; F1 += rf[w][1]; F2 += rf[w][2]; F3 += rf[w][3]; S2 += rf[w][4];
            U0 += ru[w][0]; U1 += ru[w][1]; U2 += ru[w][2]; U3 += ru[w][3];
        }
        float nl = U0 ? (float)U0 : 1.f;
        float n1 = U1 ? (float)U1 : 1.f;
        float nd = U2 ? (float)U2 : 1.f;
        float n  = U3 ? (float)U3 : 1.f;
        out[0] = F0 / nl;          // loss_l / nl
        out[1] = (F3 + S2) / n;    // loss_conf / n
        out[2] = F1 / n1;          // loss_landm / n1
        out[3] = F2 / nd;          // loss_dpth / ndpth
    }
}

extern "C" void kernel_launch(void* const* d_in, const int* in_sizes, int n_in,
                              void* d_out, int out_size, void* d_ws, size_t ws_size,
                              hipStream_t stream) {
    const float* boxes_p = (const float*)d_in[0];
    const float* conf_p  = (const float*)d_in[1];
    const float* kpts_p  = (const float*)d_in[2];
    const float* dpth_p  = (const float*)d_in[3];
    const float* boxes_t = (const float*)d_in[4];
    const float* kypts_t = (const float*)d_in[5];
    const float* dpths_t = (const float*)d_in[6];
    const int*   label   = (const int*)d_in[7];
    float* out = (float*)d_out;

    uint8_t* ws = (uint8_t*)d_ws;
    uint16_t* hist     = (uint16_t*)(ws + OFF_HIST);
    float*    bpart    = (float*)(ws + OFF_BPART);
    unsigned* bcnt     = (unsigned*)(ws + OFF_BCNT);
    int*      rowtb    = (int*)(ws + OFF_TB);
    float*    rowscale = (float*)(ws + OFF_SCALE);
    float*    part2    = (float*)(ws + OFF_PART2);

    multibox_pass1<<<NBLK, 256, 0, stream>>>(
        boxes_p, conf_p, kpts_p, dpth_p, boxes_t, kypts_t, dpths_t, label,
        hist, bpart, bcnt);

    multibox_select<<<B_, 256, 0, stream>>>(hist, bcnt, rowtb, rowscale);

    multibox_pass2<<<NBLK, 256, 0, stream>>>(conf_p, label, rowtb, rowscale, part2);

    multibox_final<<<1, 256, 0, stream>>>(bpart, bcnt, part2, out);
}

// Round 4
// 64.174 us; speedup vs baseline: 6.1785x; 1.6040x over previous
//
#include <hip/hip_runtime.h>
#include <stdint.h>

constexpr int B_ = 64;
constexpr int P_ = 65536;
constexpr int NEGPOS_ = 7;
constexpr int NBINS = 512;         // linear bins of d = c1 - c0 over [-4, 6]
constexpr int CHUNK = 2048;        // anchors per block (8 per thread, one batch)
constexpr int CPR = P_ / CHUNK;    // 32 chunks per row
constexpr int NBLK = B_ * CPR;     // 2048 blocks

__device__ __forceinline__ int bin_of(float d) {
    int b = (int)fmaf(d, 51.2f, 204.8f);
    return b < 0 ? 0 : (b > NBINS - 1 ? NBINS - 1 : b);
}
__device__ __forceinline__ float softplus(float x) {
    return fmaxf(x, 0.f) + log1pf(expf(-fabsf(x)));
}
__device__ __forceinline__ float smooth_l1(float t, float p) {
    float ad = fabsf(t - p);
    return ad < 1.0f ? 0.5f * ad * ad : ad - 0.5f;
}

// Workspace layout (every byte overwritten before read each call; no memset)
constexpr size_t OFF_HIST  = 0;                                      // NBLK*NBINS u16 (2 MB)
constexpr size_t OFF_HSUM  = OFF_HIST + (size_t)NBLK * NBINS * 2;    // NBLK*NBINS f32 (4 MB)
constexpr size_t OFF_BPART = OFF_HSUM + (size_t)NBLK * NBINS * 4;    // NBLK*4 f32
constexpr size_t OFF_BCNT  = OFF_BPART + (size_t)NBLK * 16;          // NBLK*4 u32
constexpr size_t OFF_ROWS2 = OFF_BCNT + (size_t)NBLK * 16;           // 64 f32

// ---- Pass 1: everything except the cross-block top-k selection -----------------
__global__ __launch_bounds__(256, 8) void multibox_pass1(
    const float* __restrict__ boxes_p, const float* __restrict__ conf_p,
    const float* __restrict__ kpts_p,  const float* __restrict__ dpth_p,
    const float* __restrict__ boxes_t, const float* __restrict__ kypts_t,
    const float* __restrict__ dpths_t, const int* __restrict__ label,
    uint16_t* __restrict__ hist, float* __restrict__ hsumg,
    float* __restrict__ bpart, unsigned* __restrict__ bcnt)
{
    __shared__ unsigned hcnt[NBINS];
    __shared__ float    hsum[NBINS];
    __shared__ float    redf[4][4];
    __shared__ unsigned redu[4][4];

    const int blk = blockIdx.x;
    const int row = blk / CPR, chunk = blk % CPR;
    const int t = threadIdx.x;

    hcnt[t] = 0u; hcnt[t + 256] = 0u;
    hsum[t] = 0.f; hsum[t + 256] = 0.f;
    __syncthreads();

    const long long base = (long long)row * P_ + (long long)chunk * CHUNK;
    const long long a0 = base + (long long)t * 8;

    // batched, independent streaming loads (all in flight before any use)
    const int4 labA = *(const int4*)(label + a0);
    const int4 labB = *(const int4*)(label + a0 + 4);
    const float4* cp = (const float4*)(conf_p + a0 * 2);
    const float4 c0 = cp[0], c1 = cp[1], c2 = cp[2], c3 = cp[3];

    float l_box = 0.f, l_lm = 0.f, l_dp = 0.f, l_ce = 0.f;
    unsigned c_box = 0, c_lm = 0, c_dp = 0, c_pos = 0;

    auto pos_path = [&](long long i, float d) {
        c_pos++;
        l_ce += softplus(-d);   // lse - c1
        const float4 bt = ((const float4*)boxes_t)[i];
        const float4 bp = ((const float4*)boxes_p)[i];
        if (!__builtin_isnan(bt.x)) { c_box++; l_box += smooth_l1(bt.x, bp.x); }
        if (!__builtin_isnan(bt.y)) { c_box++; l_box += smooth_l1(bt.y, bp.y); }
        if (!__builtin_isnan(bt.z)) { c_box++; l_box += smooth_l1(bt.z, bp.z); }
        if (!__builtin_isnan(bt.w)) { c_box++; l_box += smooth_l1(bt.w, bp.w); }
        const float2* kt = ((const float2*)kypts_t) + i * 5;
        const float2* kp = ((const float2*)kpts_p)  + i * 5;
        #pragma unroll
        for (int e = 0; e < 5; ++e) {
            float2 t2 = kt[e], p2 = kp[e];
            if (!__builtin_isnan(t2.x)) { c_lm++; l_lm += smooth_l1(t2.x, p2.x); }
            if (!__builtin_isnan(t2.y)) { c_lm++; l_lm += smooth_l1(t2.y, p2.y); }
        }
        const float2 dt = ((const float2*)dpths_t)[i];
        const float2 dp = ((const float2*)dpth_p)[i];
        if (!__builtin_isnan(dt.x)) { c_dp++; l_dp += smooth_l1(dt.x, dp.x); }
        if (!__builtin_isnan(dt.y)) { c_dp++; l_dp += smooth_l1(dt.y, dp.y); }
    };
    auto proc = [&](int lab, float cx, float cy, long long i) {
        const float d = cy - cx;
        if (lab != 0) {
            pos_path(i, d);
        } else {
            const int b = bin_of(d);
            atomicAdd(&hcnt[b], 1u);
            atomicAdd(&hsum[b], softplus(d));   // native ds_add_f32
        }
    };

    proc(labA.x, c0.x, c0.y, a0 + 0);
    proc(labA.y, c0.z, c0.w, a0 + 1);
    proc(labA.z, c1.x, c1.y, a0 + 2);
    proc(labA.w, c1.z, c1.w, a0 + 3);
    proc(labB.x, c2.x, c2.y, a0 + 4);
    proc(labB.y, c2.z, c2.w, a0 + 5);
    proc(labB.z, c3.x, c3.y, a0 + 6);
    proc(labB.w, c3.z, c3.w, a0 + 7);

    // block reduction of scalar partials (no atomics)
    #pragma unroll
    for (int o = 32; o > 0; o >>= 1) {
        l_box += __shfl_down(l_box, o);
        l_lm  += __shfl_down(l_lm, o);
        l_dp  += __shfl_down(l_dp, o);
        l_ce  += __shfl_down(l_ce, o);
        c_box += __shfl_down(c_box, o);
        c_lm  += __shfl_down(c_lm, o);
        c_dp  += __shfl_down(c_dp, o);
        c_pos += __shfl_down(c_pos, o);
    }
    const int wid = t >> 6;
    if ((t & 63) == 0) {
        redf[wid][0] = l_box; redf[wid][1] = l_lm; redf[wid][2] = l_dp; redf[wid][3] = l_ce;
        redu[wid][0] = c_box; redu[wid][1] = c_lm; redu[wid][2] = c_dp; redu[wid][3] = c_pos;
    }
    __syncthreads();   // also makes all histogram atomics visible
    if (t == 0) {
        float f0 = 0, f1 = 0, f2 = 0, f3 = 0; unsigned u0 = 0, u1 = 0, u2 = 0, u3 = 0;
        #pragma unroll
        for (int w = 0; w < 4; ++w) {
            f0 += redf[w][0]; f1 += redf[w][1]; f2 += redf[w][2]; f3 += redf[w][3];
            u0 += redu[w][0]; u1 += redu[w][1]; u2 += redu[w][2]; u3 += redu[w][3];
        }
        *(float4*)(bpart + (size_t)blk * 4) = make_float4(f0, f1, f2, f3);
        *(uint4*)(bcnt + (size_t)blk * 4) = make_uint4(u0, u1, u2, u3);
    }

    // flush per-block histogram: thread t owns bins 2t, 2t+1 (plain stores)
    const unsigned cA = hcnt[2 * t], cB = hcnt[2 * t + 1];
    *(ushort2*)(hist + (size_t)blk * NBINS + 2 * t) = make_ushort2((uint16_t)cA, (uint16_t)cB);
    *(float2*)(hsumg + (size_t)blk * NBINS + 2 * t) = make_float2(hsum[2 * t], hsum[2 * t + 1]);
}

// ---- Select: per-row top-k sum of mining losses from (count,sum) histograms ----
__global__ __launch_bounds__(256) void multibox_select(
    const uint16_t* __restrict__ hist, const float* __restrict__ hsumg,
    const unsigned* __restrict__ bcnt, float* __restrict__ rowS2)
{
    const int r = blockIdx.x, j = threadIdx.x;

    unsigned cnt0 = 0, cnt1 = 0; float sum0 = 0.f, sum1 = 0.f;  // my bins 2j, 2j+1
    for (int ch = 0; ch < CPR; ++ch) {
        const size_t o = (size_t)(r * CPR + ch) * NBINS + 2 * j;
        const ushort2 cv = *(const ushort2*)(hist + o);
        const float2  sv = *(const float2*)(hsumg + o);
        cnt0 += cv.x; cnt1 += cv.y; sum0 += sv.x; sum1 += sv.y;
    }
    const unsigned segc = cnt0 + cnt1;
    const float    segs = sum0 + sum1;

    __shared__ unsigned sc[256];
    __shared__ float    ss[256];
    sc[j] = segc; ss[j] = segs;
    __syncthreads();
    // inclusive suffix scan (descending bins = descending loss threshold)
    for (int off = 1; off < 256; off <<= 1) {
        unsigned ca = (j + off < 256) ? sc[j + off] : 0u;
        float    sa = (j + off < 256) ? ss[j + off] : 0.f;
        __syncthreads();
        sc[j] += ca; ss[j] += sa;
        __syncthreads();
    }
    const unsigned Tj = sc[j];       const float Sj = ss[j];
    const unsigned above = Tj - segc; const float aboves = Sj - segs;
    const unsigned T0 = sc[0];       const float S0 = ss[0];

    __shared__ unsigned snp;
    if (j < 64) {
        unsigned s = (j < CPR) ? bcnt[(size_t)(r * CPR + j) * 4 + 3] : 0u;
        #pragma unroll
        for (int o = 32; o > 0; o >>= 1) s += __shfl_down(s, o);
        if (j == 0) snp = s;
    }
    __syncthreads();

    long long k = (long long)NEGPOS_ * (long long)snp;
    if (k > P_ - 1) k = P_ - 1;

    if (k <= 0)                 { if (j == 0) rowS2[r] = 0.f; return; }
    if ((long long)T0 <= k)     { if (j == 0) rowS2[r] = S0;  return; }

    if ((long long)above < k && k <= (long long)Tj) {   // unique boundary thread
        if ((long long)(above + cnt1) >= k) {
            const unsigned rr = (unsigned)(k - above);
            rowS2[r] = aboves + (cnt1 ? sum1 * (float)rr / (float)cnt1 : 0.f);
        } else {
            const unsigned rr = (unsigned)(k - above - cnt1);
            rowS2[r] = aboves + sum1 + (cnt0 ? sum0 * (float)rr / (float)cnt0 : 0.f);
        }
    }
}

// ---- Finalize ------------------------------------------------------------------
__global__ __launch_bounds__(256) void multibox_final(
    const float* __restrict__ bpart, const unsigned* __restrict__ bcnt,
    const float* __restrict__ rowS2, float* __restrict__ out)
{
    const int t = threadIdx.x;
    float f0 = 0, f1 = 0, f2 = 0, f3 = 0;
    unsigned u0 = 0, u1 = 0, u2 = 0, u3 = 0;
    for (int i = t; i < NBLK; i += 256) {
        const float4 bp = ((const float4*)bpart)[i];
        const uint4  bc = ((const uint4*)bcnt)[i];
        f0 += bp.x; f1 += bp.y; f2 += bp.z; f3 += bp.w;
        u0 += bc.x; u1 += bc.y; u2 += bc.z; u3 += bc.w;
    }
    float s2 = (t < B_) ? rowS2[t] : 0.f;
    #pragma unroll
    for (int o = 32; o > 0; o >>= 1) {
        f0 += __shfl_down(f0, o); f1 += __shfl_down(f1, o);
        f2 += __shfl_down(f2, o); f3 += __shfl_down(f3, o);
        s2 += __shfl_down(s2, o);
        u0 += __shfl_down(u0, o); u1 += __shfl_down(u1, o);
        u2 += __shfl_down(u2, o); u3 += __shfl_down(u3, o);
    }
    __shared__ float rf[4][5];
    __shared__ unsigned ru[4][4];
    const int wid = t >> 6;
    if ((t & 63) == 0) {
        rf[wid][0] = f0; rf[wid][1] = f1; rf[wid][2] = f2; rf[wid][3] = f3; rf[wid][4] = s2;
        ru[wid][0] = u0; ru[wid][1] = u1; ru[wid][2] = u2; ru[wid][3] = u3;
    }
    __syncthreads();
    if (t == 0) {
        float F0 = 0, F1 = 0, F2 = 0, F3 = 0, S2 = 0;
        unsigned U0 = 0, U1 = 0, U2 = 0, U3 = 0;
        #pragma unroll
        for (int w = 0; w < 4; ++w) {
            F0 += rf[w][0]; F1 += rf[w][1]; F2 += rf[w][2]; F3 += rf[w][3]; S2 += rf[w][4];
            U0 += ru[w][0]; U1 += ru[w][1]; U2 += ru[w][2]; U3 += ru[w][3];
        }
        const float nl = U0 ? (float)U0 : 1.f;
        const float n1 = U1 ? (float)U1 : 1.f;
        const float nd = U2 ? (float)U2 : 1.f;
        const float n  = U3 ? (float)U3 : 1.f;
        out[0] = F0 / nl;          // loss_l / nl
        out[1] = (F3 + S2) / n;    // loss_conf / n
        out[2] = F1 / n1;          // loss_landm / n1
        out[3] = F2 / nd;          // loss_dpth / ndpth
    }
}

extern "C" void kernel_launch(void* const* d_in, const int* in_sizes, int n_in,
                              void* d_out, int out_size, void* d_ws, size_t ws_size,
                              hipStream_t stream) {
    const float* boxes_p = (const float*)d_in[0];
    const float* conf_p  = (const float*)d_in[1];
    const float* kpts_p  = (const float*)d_in[2];
    const float* dpth_p  = (const float*)d_in[3];
    const float* boxes_t = (const float*)d_in[4];
    const float* kypts_t = (const float*)d_in[5];
    const float* dpths_t = (const float*)d_in[6];
    const int*   label   = (const int*)d_in[7];
    float* out = (float*)d_out;

    uint8_t* ws = (uint8_t*)d_ws;
    uint16_t* hist  = (uint16_t*)(ws + OFF_HIST);
    float*    hsumg = (float*)(ws + OFF_HSUM);
    float*    bpart = (float*)(ws + OFF_BPART);
    unsigned* bcnt  = (unsigned*)(ws + OFF_BCNT);
    float*    rowS2 = (float*)(ws + OFF_ROWS2);

    multibox_pass1<<<NBLK, 256, 0, stream>>>(
        boxes_p, conf_p, kpts_p, dpth_p, boxes_t, kypts_t, dpths_t, label,
        hist, hsumg, bpart, bcnt);

    multibox_select<<<B_, 256, 0, stream>>>(hist, hsumg, bcnt, rowS2);

    multibox_final<<<1, 256, 0, stream>>>(bpart, bcnt, rowS2, out);
}